// Round 11
// baseline (322.997 us; speedup 1.0000x reference)
//
#include <hip/hip_runtime.h>
#include <cstdint>
#include <cstddef>

#define C_CH 128
#define T_TOK 9216
#define H_IMG 96
#define W_IMG 96
#define NSTATE 8

// scan tiling: 32 output tokens, 32-token warm-up halo each direction.
// CHUNK=32 + launch_bounds(256,8): 2016 blocks <= 2048 resident capacity ->
// 32 waves/CU (2x latency pool for the light, latency-bound scan).
#define CHUNK 32
#define RHALO 32
#define REGION (CHUNK + 2 * RHALO)   // 96

// k12 LDS geometry: Asm[128][68] (cols 0..2 = 3-token conv halo, 3 = pad,
// 4..67 = main 64 tokens), later aliased as xibuf[67][129].
#define ASTRIDE 68
#define XSTRIDE 129
#define AU_FLOATS 8704   // max(128*68, 67*129) = 8704

__device__ __forceinline__ float siluf_dev(float x) {
  return x / (1.0f + expf(-x));
}

__device__ __forceinline__ float fast_silu(float x) {
  // x * sigmoid(x) with native rcp; binary-thresholded output tolerates ~2ulp
  return __fdividef(x, 1.0f + __expf(-x));
}

// inline slot assignment (replaces k0's serial loop; ~12 iterations).
// Matches k0 exactly: first frame of each group -> -1; others get sequential
// slot ids counted across groups.
__device__ __forceinline__ int slot_of(const int* __restrict__ rec,
                                       int n_groups, int f) {
  int base = 0, sl = 0;
  for (int g = 0; g < n_groups; ++g) {
    const int L = rec[g];
    if (f < base + L) return (f == base) ? -1 : (sl + (f - base - 1));
    sl += L - 1;
    base += L;
  }
  return -1;
}

// ---------------------------------------------------------------------------
// K12: FUSED k1+k2 (+k0 folded in). Phases per 64-token tile:
//  0. vvec dot (tid<128, per-block redundant; L2-hot, order matches old k0)
//  1. stage A raw (main 64 tokens -> cols 4..67; 3-token conv halo -> 0..2)
//  2. rms prepass (main + halo) + logit init
//  3. scale Asm by ir*rms_w
//  4. GEMM chunks 2,3 (z) -> wbuf
//  5. GEMM chunks 0,1 (xi) -> registers
//  6. halo xi (384 dots; zero when m0==0)
//  7. write xibuf (aliases Asm)
//  8. conv+silu in place
//  9. projection 128->24 -> dtb, bc_g
// 10. delta softplus -> xd_g {xi, delta} float2
// Bit-identical to the R10 pipeline. LDS 39.9 KB -> 4 blocks/CU.
// ---------------------------------------------------------------------------
__global__ __launch_bounds__(256, 4) void k12_gemmproj(
    const float* __restrict__ feats, const float* __restrict__ in_proj,
    const float* __restrict__ rms_w, const float* __restrict__ mlp_w,
    const float* __restrict__ mlp_b, const float* __restrict__ out_proj_w,
    const float* __restrict__ conv_w, const float* __restrict__ conv_b,
    const float* __restrict__ x_proj_w,
    const float* __restrict__ dt_proj_w, const float* __restrict__ dt_proj_b,
    const int* __restrict__ rec, int n_groups,
    float* __restrict__ wbuf, float* __restrict__ logit,
    float* __restrict__ xd_g, float* __restrict__ bc_g)
{
  __shared__ float Asm[AU_FLOATS];     // 34.8 KB (A, later xibuf)
  __shared__ float redA[256], redB[256];
  __shared__ float irS[68];
  __shared__ float haloA[12];
  __shared__ float dtb[64 * 8];
  __shared__ float vv[128];
  const int f = blockIdx.y;
  const int s = slot_of(rec, n_groups, f);
  if (s < 0) return;
  const int m0 = blockIdx.x * 64;
  const int tid = threadIdx.x;
  const size_t rowbase = (size_t)s * T_TOK;

  // ---- 0. vvec (order identical to old k0: j ascending) ----
  if (tid < C_CH) {
    float a = 0.0f;
    for (int j = 0; j < C_CH; ++j) a += out_proj_w[tid * C_CH + j] * mlp_w[j];
    vv[tid] = a;
  }

  // ---- 1. stage A ----
  {
    const int c0 = tid >> 4;
    const int tq = (tid & 15) * 4;
    const float* src = feats + (size_t)f * C_CH * T_TOK + m0 + tq;
    #pragma unroll
    for (int i = 0; i < 8; ++i) {
      const int c = c0 + i * 16;
      const float4 x4 = *(const float4*)(src + (size_t)c * T_TOK);
      *(float4*)&Asm[c * ASTRIDE + 4 + tq] = x4;
    }
  }
  if (m0 > 0 && tid < C_CH) {          // halo tokens m0-3..m0-1 -> cols 0..2
    const float* src = feats + (size_t)f * C_CH * T_TOK + (size_t)tid * T_TOK + m0 - 3;
    Asm[tid * ASTRIDE + 0] = src[0];
    Asm[tid * ASTRIDE + 1] = src[1];
    Asm[tid * ASTRIDE + 2] = src[2];
  }
  __syncthreads();
  // ---- 2a. partials: per-token rms + logit dot, 4 threads/token ----
  {
    const int t = tid & 63;
    const int q = tid >> 6;
    float ssum = 0.0f, rm = 0.0f;
    for (int cc = q * 32; cc < q * 32 + 32; ++cc) {
      const float val = Asm[cc * ASTRIDE + 4 + t];
      ssum += val * val;
      rm += val * mlp_w[cc];
    }
    redA[tid] = ssum; redB[tid] = rm;
    if (m0 > 0 && tid < 12) {          // halo rms partials
      const int j = tid >> 2, qh = tid & 3;
      float ss = 0.0f;
      for (int cc = qh * 32; cc < qh * 32 + 32; ++cc) {
        const float v = Asm[cc * ASTRIDE + j];
        ss += v * v;
      }
      haloA[tid] = ss;
    }
  }
  __syncthreads();
  // ---- 2b. reduce ----
  if (tid < 64) {
    const int t = tid;
    const float ssum = redA[t] + redA[t + 64] + redA[t + 128] + redA[t + 192];
    const float rm   = redB[t] + redB[t + 64] + redB[t + 128] + redB[t + 192];
    const float ir = 1.0f / sqrtf(ssum * (1.0f / C_CH) + 1e-5f);
    logit[rowbase + m0 + t] = rm + mlp_b[0];
    irS[4 + t] = ir;
  } else if (m0 > 0 && tid < 67) {
    const int j = tid - 64;
    const float ss = haloA[j * 4] + haloA[j * 4 + 1] + haloA[j * 4 + 2] + haloA[j * 4 + 3];
    irS[j] = 1.0f / sqrtf(ss * (1.0f / C_CH) + 1e-5f);
  }
  __syncthreads();
  // ---- 3. scale ----
  {
    const int t = tid & 63;
    const int q = tid >> 6;
    const float ir = irS[4 + t];
    for (int cc = q * 32; cc < q * 32 + 32; ++cc)
      Asm[cc * ASTRIDE + 4 + t] = (Asm[cc * ASTRIDE + 4 + t] * ir) * rms_w[cc];
    if (m0 > 0 && tid < 12) {
      const int j = tid >> 2, qh = tid & 3;
      const float irh = irS[j];
      for (int cc = qh * 32; cc < qh * 32 + 32; ++cc)
        Asm[cc * ASTRIDE + j] = (Asm[cc * ASTRIDE + j] * irh) * rms_w[cc];
    }
  }
  __syncthreads();

  const int ti = tid >> 4;   // 0..15 -> rows ti*4..+3
  const int tc = tid & 15;   // 0..15 -> cols tc*4..+3

#define GEMM_CHUNK(N0, ACC) do {                                              \
    const float* bp = in_proj + (N0) + tc * 4;                                \
    _Pragma("unroll 8")                                                       \
    for (int k = 0; k < C_CH; ++k) {                                          \
      const float4 a4 = *(const float4*)&Asm[k * ASTRIDE + 4 + ti * 4];       \
      const float4 b4 = *(const float4*)(bp + (size_t)k * 256);               \
      ACC[0][0] += a4.x * b4.x; ACC[0][1] += a4.x * b4.y; ACC[0][2] += a4.x * b4.z; ACC[0][3] += a4.x * b4.w; \
      ACC[1][0] += a4.y * b4.x; ACC[1][1] += a4.y * b4.y; ACC[1][2] += a4.y * b4.z; ACC[1][3] += a4.y * b4.w; \
      ACC[2][0] += a4.z * b4.x; ACC[2][1] += a4.z * b4.y; ACC[2][2] += a4.z * b4.z; ACC[2][3] += a4.z * b4.w; \
      ACC[3][0] += a4.w * b4.x; ACC[3][1] += a4.w * b4.y; ACC[3][2] += a4.w * b4.z; ACC[3][3] += a4.w * b4.w; \
    } } while (0)

  // ---- 4. z chunks -> wbuf ----
  #pragma unroll
  for (int zc4 = 0; zc4 < 2; ++zc4) {
    float acc[4][4];
    #pragma unroll
    for (int i = 0; i < 4; ++i)
      #pragma unroll
      for (int j = 0; j < 4; ++j) acc[i][j] = 0.0f;
    GEMM_CHUNK(128 + zc4 * 64, acc);
    const int zc = zc4 * 64 + tc * 4;
    const float4 v4 = *(const float4*)&vv[zc];
    #pragma unroll
    for (int i = 0; i < 4; ++i) {
      const int t = m0 + ti * 4 + i;
      float4 o;
      o.x = 0.5f * siluf_dev(acc[i][0]) * v4.x;
      o.y = 0.5f * siluf_dev(acc[i][1]) * v4.y;
      o.z = 0.5f * siluf_dev(acc[i][2]) * v4.z;
      o.w = 0.5f * siluf_dev(acc[i][3]) * v4.w;
      *(float4*)&wbuf[(rowbase + t) * C_CH + zc] = o;
    }
  }

  // ---- 5. xi chunks -> registers ----
  float acc0[4][4], acc1[4][4];
  #pragma unroll
  for (int i = 0; i < 4; ++i)
    #pragma unroll
    for (int j = 0; j < 4; ++j) { acc0[i][j] = 0.0f; acc1[i][j] = 0.0f; }
  GEMM_CHUNK(0, acc0);
  GEMM_CHUNK(64, acc1);
#undef GEMM_CHUNK

  // ---- 6. halo xi (384 dots over 256 threads; zero when m0==0) ----
  float hx0 = 0.0f, hx1 = 0.0f;
  {
    const int j0 = tid >> 7;           // 0 or 1
    const int cc0 = tid & 127;
    if (m0 > 0) {
      for (int k = 0; k < C_CH; ++k) {
        const float b0v = in_proj[(size_t)k * 256 + cc0];
        hx0 += Asm[k * ASTRIDE + j0] * b0v;
        if (tid < 128) hx1 += Asm[k * ASTRIDE + 2] * in_proj[(size_t)k * 256 + tid];
      }
    }
  }
  __syncthreads();                     // all Asm reads complete

  // ---- 7. write xibuf (aliases Asm): rows 0..2 halo, 3..66 main ----
  {
    #pragma unroll
    for (int i = 0; i < 4; ++i) {
      const int row = 3 + ti * 4 + i;
      #pragma unroll
      for (int j = 0; j < 4; ++j) {
        Asm[row * XSTRIDE + tc * 4 + j] = acc0[i][j];
        Asm[row * XSTRIDE + 64 + tc * 4 + j] = acc1[i][j];
      }
    }
    Asm[(tid >> 7) * XSTRIDE + (tid & 127)] = hx0;
    if (tid < 128) Asm[2 * XSTRIDE + tid] = hx1;
  }
  __syncthreads();

  // ---- 8. conv + silu in place ----
  const int c = tid & 127;
  const int half = tid >> 7;
  {
    const float4 cw = *(const float4*)(conv_w + c * 4);
    const float cb = conv_b[c];
    const int row0 = half ? 35 : 3;    // first output row
    float xm1 = Asm[(row0 - 1) * XSTRIDE + c];
    float xm2 = Asm[(row0 - 2) * XSTRIDE + c];
    float xm3 = Asm[(row0 - 3) * XSTRIDE + c];
    __syncthreads();                   // prefixes safe before overwrite
    #pragma unroll
    for (int i = 0; i < 32; ++i) {
      const int row = row0 + i;
      const float cur = Asm[row * XSTRIDE + c];
      const float sum = cw.x * xm3 + cw.y * xm2 + cw.z * xm1 + cw.w * cur + cb;
      Asm[row * XSTRIDE + c] = fast_silu(sum);
      xm3 = xm2; xm2 = xm1; xm1 = cur;
    }
  }
  __syncthreads();

  // ---- 9. projection 128->24 -> dtb, bc_g ----
  {
    const int q6 = __builtin_amdgcn_readfirstlane(tid >> 6) * 6;
    const int tok = tid & 63;
    float acc[6] = {0, 0, 0, 0, 0, 0};
    for (int cc = 0; cc < C_CH; ++cc) {
      const float xv = Asm[(3 + tok) * XSTRIDE + cc];
      #pragma unroll
      for (int jj = 0; jj < 6; ++jj)
        acc[jj] += xv * x_proj_w[cc * 24 + q6 + jj];   // scalar (uniform idx)
    }
    #pragma unroll
    for (int jj = 0; jj < 6; ++jj) {
      const int o = q6 + jj;                // wave-uniform
      if (o < 8) dtb[tok * 8 + o] = acc[jj];
      else       bc_g[(rowbase + m0 + tok) * 16 + (o - 8)] = acc[jj];
    }
  }
  __syncthreads();

  // ---- 10. delta + xd interleave ----
  {
    float dw[8];
    #pragma unroll
    for (int r = 0; r < 8; ++r) dw[r] = dt_proj_w[r * C_CH + c];
    const float bias = dt_proj_b[c];
    for (int i = 0; i < 32; ++i) {
      const int tok = half * 32 + i;
      const float4 d0 = *(const float4*)&dtb[tok * 8];      // broadcast
      const float4 d1 = *(const float4*)&dtb[tok * 8 + 4];
      float pre = bias;
      pre += d0.x * dw[0] + d0.y * dw[1] + d0.z * dw[2] + d0.w * dw[3];
      pre += d1.x * dw[4] + d1.y * dw[5] + d1.z * dw[6] + d1.w * dw[7];
      const float dlt = fmaxf(pre, 0.0f) + __logf(1.0f + __expf(-fabsf(pre)));
      float2 xd;
      xd.x = Asm[(3 + tok) * XSTRIDE + c];
      xd.y = dlt;
      *(float2*)&xd_g[(rowbase + m0 + tok) * (2 * C_CH) + c * 2] = xd;
    }
  }
}

// ---------------------------------------------------------------------------
// K3_scan: pure bidirectional h-recurrence. Block = 256 threads = one
// 32-token chunk, waves 0-1 fwd / waves 2-3 bwd. Region [c0-32, c0+64),
// 64 steps per direction. 2016 blocks x 8 blocks/CU (LDS 6.4 KB,
// launch_bounds(256,8)) = 32 waves/CU, single residency round.
// Arithmetic order identical -> bit-identical logits.
// ---------------------------------------------------------------------------
__global__ __launch_bounds__(256, 8) void k3_scan(
    const float* __restrict__ xd_g, const float* __restrict__ wbuf,
    const float* __restrict__ bc_g,
    const float* __restrict__ A_log_f, const float* __restrict__ A_log_b,
    const float* __restrict__ D_f, const float* __restrict__ D_b,
    const int* __restrict__ rec, int n_groups, float* __restrict__ logit)
{
  __shared__ float bc[REGION * 16];       // 6.1 KB [region_row][0:8=B 8:16=C]
  const int f = blockIdx.y;
  const int s = slot_of(rec, n_groups, f);
  if (s < 0) return;
  const int c0 = blockIdx.x * CHUNK;
  const int r0 = c0 - RHALO;              // region start (may be negative)
  const int tid = threadIdx.x;
  const int c = tid & 127;                // channel
  const int half = tid >> 7;              // 0 = fwd waves, 1 = bwd waves
  const size_t rowbase = (size_t)s * T_TOK;

  // ---- stage B,C region slice: 96 rows x 16 floats = 384 float4 ----
  {
    const long grow = ((long)rowbase + r0) * 16;
    const int lo  = (r0 < 0) ? (-r0) * 4 : 0;
    const int hi  = (r0 + REGION > T_TOK) ? (T_TOK - r0) * 4 : REGION * 4;
    #pragma unroll
    for (int i = 0; i < 2; ++i) {
      const int idx = tid + i * 256;
      if (idx >= lo && idx < hi)
        *(float4*)&bc[idx * 4] = *(const float4*)&bc_g[grow + (long)idx * 4];
    }
  }
  __syncthreads();

  // ---- Scan setup ----
  float Ac[8];
  const float* Alog = half ? A_log_b : A_log_f;
  #pragma unroll
  for (int n = 0; n < NSTATE; ++n) Ac[n] = -expf(Alog[c * NSTATE + n]);
  const float Dd = half ? D_b[c] : D_f[c];
  float h[8] = {0, 0, 0, 0, 0, 0, 0, 0};

  // fast-decay eligibility: Ac[n] == (n+1)*Ac[0] (holds for this problem's A)
  const float a0 = Ac[0];
  int okl = 1;
  #pragma unroll
  for (int n = 1; n < NSTATE; ++n)
    okl &= (fabsf(Ac[n] - (float)(n + 1) * a0) <= 1e-4f * fabsf(Ac[n])) ? 1 : 0;
  const bool fastA = (__all(okl) != 0);   // wave-uniform

  auto decay8 = [&](float dlt, float* dA) {
    if (fastA) {
      const float e1 = __expf(dlt * a0);
      const float e2 = e1 * e1, e3 = e2 * e1, e4 = e2 * e2;
      dA[0] = e1; dA[1] = e2; dA[2] = e3; dA[3] = e4;
      dA[4] = e4 * e1; dA[5] = e4 * e2; dA[6] = e4 * e3; dA[7] = e4 * e4;
    } else {
      #pragma unroll
      for (int n = 0; n < NSTATE; ++n) dA[n] = __expf(dlt * Ac[n]);
    }
  };

  if (half == 0) {
    // forward: t from tb to c0+CHUNK-1
    const int tb = (r0 < 0) ? 0 : r0;
    const int outg0 = (c0 - tb) >> 3;        // first output group (4 or 0)
    const int ng = (c0 + CHUNK - tb) >> 3;   // 8 or 4
    for (int g = 0; g < ng; ++g) {
      const int t0 = tb + g * 8;
      const bool out = (g >= outg0);
      float xg[8], dg[8], wg[8];
      #pragma unroll
      for (int j = 0; j < 8; ++j) {
        const size_t r = rowbase + t0 + j;
        const float2 xd = *(const float2*)&xd_g[r * (2 * C_CH) + c * 2];
        xg[j] = xd.x;
        dg[j] = xd.y;
        wg[j] = out ? wbuf[r * C_CH + c] : 0.0f;
      }
      #pragma unroll
      for (int j = 0; j < 8; ++j) {
        const int t = t0 + j;
        const int p = t - r0;
        const float dlt = dg[j];
        const float xiv = xg[j];
        const float u = dlt * xiv;
        const float4 b0 = *(const float4*)&bc[p * 16];
        const float4 b1 = *(const float4*)&bc[p * 16 + 4];
        float dA[8];
        decay8(dlt, dA);
        h[0] = dA[0] * h[0] + u * b0.x;
        h[1] = dA[1] * h[1] + u * b0.y;
        h[2] = dA[2] * h[2] + u * b0.z;
        h[3] = dA[3] * h[3] + u * b0.w;
        h[4] = dA[4] * h[4] + u * b1.x;
        h[5] = dA[5] * h[5] + u * b1.y;
        h[6] = dA[6] * h[6] + u * b1.z;
        h[7] = dA[7] * h[7] + u * b1.w;
        if (out) {
          const float4 cc0 = *(const float4*)&bc[p * 16 + 8];
          const float4 cc1 = *(const float4*)&bc[p * 16 + 12];
          float y = xiv * Dd;
          y += h[0] * cc0.x + h[1] * cc0.y + h[2] * cc0.z + h[3] * cc0.w;
          y += h[4] * cc1.x + h[5] * cc1.y + h[6] * cc1.z + h[7] * cc1.w;
          float contrib = y * wg[j];
          contrib += __shfl_xor(contrib, 1);
          contrib += __shfl_xor(contrib, 2);
          contrib += __shfl_xor(contrib, 4);
          contrib += __shfl_xor(contrib, 8);
          contrib += __shfl_xor(contrib, 16);
          contrib += __shfl_xor(contrib, 32);
          if ((tid & 63) == 0) atomicAdd(&logit[rowbase + t], contrib);
        }
      }
    }
  } else {
    // backward: t from te2-1 down to c0
    const int te2e = r0 + REGION;
    const int te2 = (te2e > T_TOK) ? T_TOK : te2e;
    const int outg0 = (te2 - (c0 + CHUNK)) >> 3;  // 4 or 0
    const int ng = (te2 - c0) >> 3;               // 8 or 4
    for (int g = 0; g < ng; ++g) {
      const int t0 = te2 - 1 - g * 8;
      const bool out = (g >= outg0);
      float xg[8], dg[8], wg[8];
      #pragma unroll
      for (int j = 0; j < 8; ++j) {
        const size_t r = rowbase + t0 - j;
        const float2 xd = *(const float2*)&xd_g[r * (2 * C_CH) + c * 2];
        xg[j] = xd.x;
        dg[j] = xd.y;
        wg[j] = out ? wbuf[r * C_CH + c] : 0.0f;
      }
      #pragma unroll
      for (int j = 0; j < 8; ++j) {
        const int t = t0 - j;
        const int p = t - r0;
        const float dlt = dg[j];
        const float xiv = xg[j];
        const float u = dlt * xiv;
        const float4 b0 = *(const float4*)&bc[p * 16];
        const float4 b1 = *(const float4*)&bc[p * 16 + 4];
        float dA[8];
        decay8(dlt, dA);
        h[0] = dA[0] * h[0] + u * b0.x;
        h[1] = dA[1] * h[1] + u * b0.y;
        h[2] = dA[2] * h[2] + u * b0.z;
        h[3] = dA[3] * h[3] + u * b0.w;
        h[4] = dA[4] * h[4] + u * b1.x;
        h[5] = dA[5] * h[5] + u * b1.y;
        h[6] = dA[6] * h[6] + u * b1.z;
        h[7] = dA[7] * h[7] + u * b1.w;
        if (out) {
          const float4 cc0 = *(const float4*)&bc[p * 16 + 8];
          const float4 cc1 = *(const float4*)&bc[p * 16 + 12];
          float y = xiv * Dd;
          y += h[0] * cc0.x + h[1] * cc0.y + h[2] * cc0.z + h[3] * cc0.w;
          y += h[4] * cc1.x + h[5] * cc1.y + h[6] * cc1.z + h[7] * cc1.w;
          float contrib = y * wg[j];
          contrib += __shfl_xor(contrib, 1);
          contrib += __shfl_xor(contrib, 2);
          contrib += __shfl_xor(contrib, 4);
          contrib += __shfl_xor(contrib, 8);
          contrib += __shfl_xor(contrib, 16);
          contrib += __shfl_xor(contrib, 32);
          if ((tid & 63) == 0) atomicAdd(&logit[rowbase + t], contrib);
        }
      }
    }
  }
}

// ---------------------------------------------------------------------------
// K4: threshold (sigmoid(lg)>0.5 <=> lg>0, exact) + 3x3 max pool. ego -> 1.
// ---------------------------------------------------------------------------
__global__ __launch_bounds__(128) void k4_pool(
    const float* __restrict__ logit, const int* __restrict__ rec, int n_groups,
    float* __restrict__ out)
{
  const int w = threadIdx.x;
  if (w >= W_IMG) return;
  const int hh = blockIdx.x;
  const int f = blockIdx.y;
  const int s = slot_of(rec, n_groups, f);
  float m = 0.0f;
  if (s < 0) {
    m = 1.0f;
  } else {
    for (int dh = -1; dh <= 1; ++dh) {
      const int h2 = hh + dh;
      if (h2 < 0 || h2 >= H_IMG) continue;
      for (int dw = -1; dw <= 1; ++dw) {
        const int w2 = w + dw;
        if (w2 < 0 || w2 >= W_IMG) continue;
        if (logit[(size_t)s * T_TOK + h2 * W_IMG + w2] > 0.0f) m = 1.0f;
      }
    }
  }
  out[(size_t)f * T_TOK + hh * W_IMG + w] = m;
}

// ---------------------------------------------------------------------------
extern "C" void kernel_launch(void* const* d_in, const int* in_sizes, int n_in,
                              void* d_out, int out_size, void* d_ws, size_t ws_size,
                              hipStream_t stream) {
  const float* feats      = (const float*)d_in[0];
  const float* in_proj    = (const float*)d_in[1];
  const float* conv_w     = (const float*)d_in[2];
  const float* conv_b     = (const float*)d_in[3];
  const float* x_proj_w   = (const float*)d_in[4];
  const float* dt_proj_w  = (const float*)d_in[5];
  const float* dt_proj_b  = (const float*)d_in[6];
  const float* A_log_f    = (const float*)d_in[7];
  const float* A_log_b    = (const float*)d_in[8];
  const float* D_f        = (const float*)d_in[9];
  const float* D_b        = (const float*)d_in[10];
  const float* out_proj_w = (const float*)d_in[11];
  const float* rms_w      = (const float*)d_in[12];
  const float* mlp_w      = (const float*)d_in[13];
  const float* mlp_b      = (const float*)d_in[14];
  const int*   rec        = (const int*)d_in[15];   // int32! (jax downcasts int64)

  const int N = in_sizes[0] / (C_CH * T_TOK);
  const int n_groups = in_sizes[15];
  int S = N - n_groups;
  if (S < 1) S = 1;

  // workspace carve-up (~104 MB at S=7)
  char* p = (char*)d_ws;
  float* logit = (float*)p; p += (size_t)S * T_TOK * 4;
  float* wA    = (float*)p; p += (size_t)S * T_TOK * C_CH * 4;
  float* xd    = (float*)p; p += (size_t)S * T_TOK * (2 * C_CH) * 4;  // {xi,delta}
  float* bcg   = (float*)p; p += (size_t)S * T_TOK * 16 * 4;
  (void)ws_size; (void)n_in; (void)out_size;

  k12_gemmproj<<<dim3(T_TOK / 64, N), 256, 0, stream>>>(
      feats, in_proj, rms_w, mlp_w, mlp_b, out_proj_w,
      conv_w, conv_b, x_proj_w, dt_proj_w, dt_proj_b, rec, n_groups,
      wA, logit, xd, bcg);
  k3_scan<<<dim3(T_TOK / CHUNK, N), 256, 0, stream>>>(
      xd, wA, bcg, A_log_f, A_log_b, D_f, D_b, rec, n_groups, logit);
  k4_pool<<<dim3(H_IMG, N), 128, 0, stream>>>(logit, rec, n_groups, (float*)d_out);
}

// Round 12
// 309.495 us; speedup vs baseline: 1.0436x; 1.0436x over previous
//
#include <hip/hip_runtime.h>
#include <cstdint>
#include <cstddef>

#define C_CH 128
#define T_TOK 9216
#define H_IMG 96
#define W_IMG 96
#define NSTATE 8

// scan tiling: 64 output tokens, 32-token warm-up halo each direction (R10 cfg).
#define CHUNK 64
#define RHALO 32
#define REGION (CHUNK + 2 * RHALO)   // 128

// k12 LDS geometry: Asm[128][68] (cols 0..2 = 3-token conv halo, 3 = pad,
// 4..67 = main 64 tokens), later aliased as xibuf[67][129].
#define ASTRIDE 68
#define XSTRIDE 129
#define AU_FLOATS 8704   // max(128*68, 67*129) = 8704

// B bf16-split planes: [plane(3)][kg(16)][n(256)][i(8)] ushort; plane stride 32768
#define BPLANE 32768

typedef __attribute__((ext_vector_type(8))) short short8v;
typedef __attribute__((ext_vector_type(4))) float f32x4;

__device__ __forceinline__ float siluf_dev(float x) {
  return x / (1.0f + expf(-x));
}

__device__ __forceinline__ float fast_silu(float x) {
  return __fdividef(x, 1.0f + __expf(-x));
}

__device__ __forceinline__ unsigned short bf16_rne(float x) {
  unsigned int u = __float_as_uint(x);
  unsigned int r = u + 0x7FFFu + ((u >> 16) & 1u);
  return (unsigned short)(r >> 16);
}
__device__ __forceinline__ float bf16_tof(unsigned short h) {
  return __uint_as_float(((unsigned int)h) << 16);
}

// ---------------------------------------------------------------------------
// K0: slot assignment + vvec (block 0) + in_proj 3-way bf16 split (blocks 1..32)
// Split: a = hi + mid + lo (each bf16 RNE); residual ~2^-27 |a|.
// ---------------------------------------------------------------------------
__global__ __launch_bounds__(256) void k0_setup(
    const int* __restrict__ rec, int n_groups, int N,
    const float* __restrict__ out_proj_w, const float* __restrict__ mlp_w,
    const float* __restrict__ in_proj,
    float* __restrict__ vvec, int* __restrict__ slot,
    unsigned short* __restrict__ Bpk)
{
  const int bid = blockIdx.x;
  const int tid = threadIdx.x;
  if (bid == 0) {
    if (tid == 0) {
      int f = 0, sl = 0;
      for (int g = 0; g < n_groups; ++g) {
        const int L = rec[g];
        slot[f] = -1;
        for (int i = 1; i < L; ++i) slot[f + i] = sl++;
        f += L;
      }
    }
    if (tid < C_CH) {
      float acc = 0.0f;
      for (int j = 0; j < C_CH; ++j) acc += out_proj_w[tid * C_CH + j] * mlp_w[j];
      vvec[tid] = acc;
    }
  } else {
    const int flat = (bid - 1) * 256 + tid;    // 0..8191
    #pragma unroll
    for (int e = 0; e < 4; ++e) {
      const int el = flat * 4 + e;             // 0..32767 = k*256+n
      const int k = el >> 8, n = el & 255;
      const float a = in_proj[el];
      const unsigned short h = bf16_rne(a);
      const float r1 = a - bf16_tof(h);
      const unsigned short md = bf16_rne(r1);
      const unsigned short lo = bf16_rne(r1 - bf16_tof(md));
      const int kg = k >> 3, i = k & 7;
      const size_t base = ((size_t)kg * 256 + n) * 8 + i;
      Bpk[base] = h;
      Bpk[BPLANE + base] = md;
      Bpk[2 * BPLANE + base] = lo;
    }
  }
}

// ---------------------------------------------------------------------------
// K12: fused rmsnorm + xz-GEMM (bf16 3-split MFMA) + conv + projection + delta.
// GEMM: D = A(64x128) . B(128x256) via mfma_f32_16x16x32_bf16.
//  - wave w owns token rows 16w..16w+15, all 16 col tiles; acc f32x4[16].
//  - A-frag: lane l holds A[row=l&15][k=32q+(l>>4)*8+i], split 3-way on the
//    fly from fp32 LDS. B-frag: 16B loads from pre-split Bpk planes.
//    (k->position mapping cancels between A and B; row/col mapping per m89.)
//  - 6 cross-products (hh,hm,mh,hl,mm,lh): rel err ~2^-26, below the already
//    accepted fast_silu perturbation; binary output unaffected.
//  - D layout: col=lane&15, row=(lane>>4)*4+r  ->  token = m0+16w+(l>>4)*4+r.
// Other phases identical to R10. LDS 39.4 KB -> 4 blocks/CU.
// ---------------------------------------------------------------------------
__global__ __launch_bounds__(256, 4) void k12_gemmproj(
    const float* __restrict__ feats, const float* __restrict__ in_proj,
    const float* __restrict__ rms_w, const float* __restrict__ mlp_w,
    const float* __restrict__ mlp_b, const float* __restrict__ vvec,
    const float* __restrict__ conv_w, const float* __restrict__ conv_b,
    const float* __restrict__ x_proj_w,
    const float* __restrict__ dt_proj_w, const float* __restrict__ dt_proj_b,
    const int* __restrict__ slot, const unsigned short* __restrict__ Bpk,
    float* __restrict__ wbuf, float* __restrict__ logit,
    float* __restrict__ xd_g, float* __restrict__ bc_g)
{
  __shared__ float Asm[AU_FLOATS];     // 34.8 KB (A, later xibuf)
  __shared__ float redA[256], redB[256];
  __shared__ float irS[68];
  __shared__ float haloA[12];
  __shared__ float dtb[64 * 8];
  const int f = blockIdx.y;
  const int s = slot[f];
  if (s < 0) return;
  const int m0 = blockIdx.x * 64;
  const int tid = threadIdx.x;
  const size_t rowbase = (size_t)s * T_TOK;

  // ---- 1. stage A ----
  {
    const int c0 = tid >> 4;
    const int tq = (tid & 15) * 4;
    const float* src = feats + (size_t)f * C_CH * T_TOK + m0 + tq;
    #pragma unroll
    for (int i = 0; i < 8; ++i) {
      const int c = c0 + i * 16;
      const float4 x4 = *(const float4*)(src + (size_t)c * T_TOK);
      *(float4*)&Asm[c * ASTRIDE + 4 + tq] = x4;
    }
  }
  if (m0 > 0 && tid < C_CH) {          // halo tokens m0-3..m0-1 -> cols 0..2
    const float* src = feats + (size_t)f * C_CH * T_TOK + (size_t)tid * T_TOK + m0 - 3;
    Asm[tid * ASTRIDE + 0] = src[0];
    Asm[tid * ASTRIDE + 1] = src[1];
    Asm[tid * ASTRIDE + 2] = src[2];
  }
  __syncthreads();
  // ---- 2a. partials: per-token rms + logit dot, 4 threads/token ----
  {
    const int t = tid & 63;
    const int q = tid >> 6;
    float ssum = 0.0f, rm = 0.0f;
    for (int cc = q * 32; cc < q * 32 + 32; ++cc) {
      const float val = Asm[cc * ASTRIDE + 4 + t];
      ssum += val * val;
      rm += val * mlp_w[cc];
    }
    redA[tid] = ssum; redB[tid] = rm;
    if (m0 > 0 && tid < 12) {          // halo rms partials
      const int j = tid >> 2, qh = tid & 3;
      float ss = 0.0f;
      for (int cc = qh * 32; cc < qh * 32 + 32; ++cc) {
        const float v = Asm[cc * ASTRIDE + j];
        ss += v * v;
      }
      haloA[tid] = ss;
    }
  }
  __syncthreads();
  // ---- 2b. reduce ----
  if (tid < 64) {
    const int t = tid;
    const float ssum = redA[t] + redA[t + 64] + redA[t + 128] + redA[t + 192];
    const float rm   = redB[t] + redB[t + 64] + redB[t + 128] + redB[t + 192];
    const float ir = 1.0f / sqrtf(ssum * (1.0f / C_CH) + 1e-5f);
    logit[rowbase + m0 + t] = rm + mlp_b[0];
    irS[4 + t] = ir;
  } else if (m0 > 0 && tid < 67) {
    const int j = tid - 64;
    const float ss = haloA[j * 4] + haloA[j * 4 + 1] + haloA[j * 4 + 2] + haloA[j * 4 + 3];
    irS[j] = 1.0f / sqrtf(ss * (1.0f / C_CH) + 1e-5f);
  }
  __syncthreads();
  // ---- 3. scale ----
  {
    const int t = tid & 63;
    const int q = tid >> 6;
    const float ir = irS[4 + t];
    for (int cc = q * 32; cc < q * 32 + 32; ++cc)
      Asm[cc * ASTRIDE + 4 + t] = (Asm[cc * ASTRIDE + 4 + t] * ir) * rms_w[cc];
    if (m0 > 0 && tid < 12) {
      const int j = tid >> 2, qh = tid & 3;
      const float irh = irS[j];
      for (int cc = qh * 32; cc < qh * 32 + 32; ++cc)
        Asm[cc * ASTRIDE + j] = (Asm[cc * ASTRIDE + j] * irh) * rms_w[cc];
    }
  }
  __syncthreads();

  // ---- 4+5. MFMA GEMM: all 16 col tiles ----
  const int wv = tid >> 6;           // wave 0..3 -> token rows 16wv..+15
  const int l  = tid & 63;
  const int ln = l & 15;             // A-row / B-col / D-col lane index
  const int kg = l >> 4;             // k subgroup within K=32
  const int drow0 = kg * 4;          // D row base within 16x16 tile

  f32x4 acc[16];
  #pragma unroll
  for (int t = 0; t < 16; ++t) acc[t] = (f32x4){0.f, 0.f, 0.f, 0.f};

  #pragma unroll
  for (int q = 0; q < 4; ++q) {
    short8v Ah, Am, Al;
    #pragma unroll
    for (int i = 0; i < 8; ++i) {
      const int k = 32 * q + kg * 8 + i;
      const float a = Asm[k * ASTRIDE + 4 + 16 * wv + ln];
      const unsigned short h = bf16_rne(a);
      const float r1 = a - bf16_tof(h);
      const unsigned short md = bf16_rne(r1);
      const unsigned short lo = bf16_rne(r1 - bf16_tof(md));
      Ah[i] = (short)h; Am[i] = (short)md; Al[i] = (short)lo;
    }
    const unsigned short* bq = Bpk + ((size_t)(4 * q + kg) * 256 + ln) * 8;
    #pragma unroll
    for (int t = 0; t < 16; ++t) {
      const unsigned short* bp = bq + (size_t)t * 128;   // 16 cols * 8
      const short8v Bh = *(const short8v*)(bp);
      const short8v Bm = *(const short8v*)(bp + BPLANE);
      const short8v Bl = *(const short8v*)(bp + 2 * BPLANE);
      acc[t] = __builtin_amdgcn_mfma_f32_16x16x32_bf16(Ah, Bh, acc[t], 0, 0, 0);
      acc[t] = __builtin_amdgcn_mfma_f32_16x16x32_bf16(Ah, Bm, acc[t], 0, 0, 0);
      acc[t] = __builtin_amdgcn_mfma_f32_16x16x32_bf16(Am, Bh, acc[t], 0, 0, 0);
      acc[t] = __builtin_amdgcn_mfma_f32_16x16x32_bf16(Ah, Bl, acc[t], 0, 0, 0);
      acc[t] = __builtin_amdgcn_mfma_f32_16x16x32_bf16(Am, Bm, acc[t], 0, 0, 0);
      acc[t] = __builtin_amdgcn_mfma_f32_16x16x32_bf16(Al, Bh, acc[t], 0, 0, 0);
    }
  }

  // ---- z epilogue (tiles 8..15 = channels 128..255) -> wbuf (global) ----
  #pragma unroll
  for (int t = 8; t < 16; ++t) {
    const int ch = (t - 8) * 16 + ln;
    const float v = vvec[ch];
    #pragma unroll
    for (int r = 0; r < 4; ++r) {
      const int tok = m0 + 16 * wv + drow0 + r;
      wbuf[(rowbase + tok) * C_CH + ch] = 0.5f * siluf_dev(acc[t][r]) * v;
    }
  }

  // ---- 6. halo xi (384 dots over 256 threads; zero when m0==0) ----
  float hx0 = 0.0f, hx1 = 0.0f;
  {
    const int j0 = tid >> 7;           // 0 or 1
    const int cc0 = tid & 127;
    if (m0 > 0) {
      for (int k = 0; k < C_CH; ++k) {
        const float b0v = in_proj[(size_t)k * 256 + cc0];
        hx0 += Asm[k * ASTRIDE + j0] * b0v;
        if (tid < 128) hx1 += Asm[k * ASTRIDE + 2] * in_proj[(size_t)k * 256 + tid];
      }
    }
  }
  __syncthreads();                     // all Asm reads complete

  // ---- 7. write xibuf (aliases Asm): rows 0..2 halo, 3..66 main ----
  {
    #pragma unroll
    for (int t = 0; t < 8; ++t) {
      const int ch = t * 16 + ln;
      #pragma unroll
      for (int r = 0; r < 4; ++r) {
        const int row = 3 + 16 * wv + drow0 + r;
        Asm[row * XSTRIDE + ch] = acc[t][r];
      }
    }
    Asm[(tid >> 7) * XSTRIDE + (tid & 127)] = hx0;
    if (tid < 128) Asm[2 * XSTRIDE + tid] = hx1;
  }
  __syncthreads();

  // ---- 8. conv + silu in place ----
  const int c = tid & 127;
  const int half = tid >> 7;
  {
    const float4 cw = *(const float4*)(conv_w + c * 4);
    const float cb = conv_b[c];
    const int row0 = half ? 35 : 3;    // first output row
    float xm1 = Asm[(row0 - 1) * XSTRIDE + c];
    float xm2 = Asm[(row0 - 2) * XSTRIDE + c];
    float xm3 = Asm[(row0 - 3) * XSTRIDE + c];
    __syncthreads();                   // prefixes safe before overwrite
    #pragma unroll
    for (int i = 0; i < 32; ++i) {
      const int row = row0 + i;
      const float cur = Asm[row * XSTRIDE + c];
      const float sum = cw.x * xm3 + cw.y * xm2 + cw.z * xm1 + cw.w * cur + cb;
      Asm[row * XSTRIDE + c] = fast_silu(sum);
      xm3 = xm2; xm2 = xm1; xm1 = cur;
    }
  }
  __syncthreads();

  // ---- 9. projection 128->24 -> dtb, bc_g ----
  {
    const int q6 = __builtin_amdgcn_readfirstlane(tid >> 6) * 6;
    const int tok = tid & 63;
    float acp[6] = {0, 0, 0, 0, 0, 0};
    for (int cc = 0; cc < C_CH; ++cc) {
      const float xv = Asm[(3 + tok) * XSTRIDE + cc];
      #pragma unroll
      for (int jj = 0; jj < 6; ++jj)
        acp[jj] += xv * x_proj_w[cc * 24 + q6 + jj];   // scalar (uniform idx)
    }
    #pragma unroll
    for (int jj = 0; jj < 6; ++jj) {
      const int o = q6 + jj;                // wave-uniform
      if (o < 8) dtb[tok * 8 + o] = acp[jj];
      else       bc_g[(rowbase + m0 + tok) * 16 + (o - 8)] = acp[jj];
    }
  }
  __syncthreads();

  // ---- 10. delta + xd interleave ----
  {
    float dw[8];
    #pragma unroll
    for (int r = 0; r < 8; ++r) dw[r] = dt_proj_w[r * C_CH + c];
    const float bias = dt_proj_b[c];
    for (int i = 0; i < 32; ++i) {
      const int tok = half * 32 + i;
      const float4 d0 = *(const float4*)&dtb[tok * 8];      // broadcast
      const float4 d1 = *(const float4*)&dtb[tok * 8 + 4];
      float pre = bias;
      pre += d0.x * dw[0] + d0.y * dw[1] + d0.z * dw[2] + d0.w * dw[3];
      pre += d1.x * dw[4] + d1.y * dw[5] + d1.z * dw[6] + d1.w * dw[7];
      const float dlt = fmaxf(pre, 0.0f) + __logf(1.0f + __expf(-fabsf(pre)));
      float2 xd;
      xd.x = Asm[(3 + tok) * XSTRIDE + c];
      xd.y = dlt;
      *(float2*)&xd_g[(rowbase + m0 + tok) * (2 * C_CH) + c * 2] = xd;
    }
  }
}

// ---------------------------------------------------------------------------
// K3_scan: pure bidirectional h-recurrence (R10 config: CHUNK=64, 4 blk/CU).
// ---------------------------------------------------------------------------
__global__ __launch_bounds__(256, 4) void k3_scan(
    const float* __restrict__ xd_g, const float* __restrict__ wbuf,
    const float* __restrict__ bc_g,
    const float* __restrict__ A_log_f, const float* __restrict__ A_log_b,
    const float* __restrict__ D_f, const float* __restrict__ D_b,
    const int* __restrict__ slot, float* __restrict__ logit)
{
  __shared__ float bc[REGION * 16];       // 8.2 KB [region_row][0:8=B 8:16=C]
  const int f = blockIdx.y;
  const int s = slot[f];
  if (s < 0) return;
  const int c0 = blockIdx.x * CHUNK;
  const int r0 = c0 - RHALO;              // region start (may be negative)
  const int tid = threadIdx.x;
  const int c = tid & 127;                // channel
  const int half = tid >> 7;              // 0 = fwd waves, 1 = bwd waves
  const size_t rowbase = (size_t)s * T_TOK;

  // ---- stage B,C region slice: 128 rows x 16 floats = 512 float4 ----
  {
    const long grow = ((long)rowbase + r0) * 16;
    const int lo  = (r0 < 0) ? (-r0) * 4 : 0;
    const int hi  = (r0 + REGION > T_TOK) ? (T_TOK - r0) * 4 : REGION * 4;
    #pragma unroll
    for (int i = 0; i < 2; ++i) {
      const int idx = tid + i * 256;
      if (idx >= lo && idx < hi)
        *(float4*)&bc[idx * 4] = *(const float4*)&bc_g[grow + (long)idx * 4];
    }
  }
  __syncthreads();

  // ---- Scan setup ----
  float Ac[8];
  const float* Alog = half ? A_log_b : A_log_f;
  #pragma unroll
  for (int n = 0; n < NSTATE; ++n) Ac[n] = -expf(Alog[c * NSTATE + n]);
  const float Dd = half ? D_b[c] : D_f[c];
  float h[8] = {0, 0, 0, 0, 0, 0, 0, 0};

  // fast-decay eligibility: Ac[n] == (n+1)*Ac[0] (holds for this problem's A)
  const float a0 = Ac[0];
  int okl = 1;
  #pragma unroll
  for (int n = 1; n < NSTATE; ++n)
    okl &= (fabsf(Ac[n] - (float)(n + 1) * a0) <= 1e-4f * fabsf(Ac[n])) ? 1 : 0;
  const bool fastA = (__all(okl) != 0);   // wave-uniform

  auto decay8 = [&](float dlt, float* dA) {
    if (fastA) {
      const float e1 = __expf(dlt * a0);
      const float e2 = e1 * e1, e3 = e2 * e1, e4 = e2 * e2;
      dA[0] = e1; dA[1] = e2; dA[2] = e3; dA[3] = e4;
      dA[4] = e4 * e1; dA[5] = e4 * e2; dA[6] = e4 * e3; dA[7] = e4 * e4;
    } else {
      #pragma unroll
      for (int n = 0; n < NSTATE; ++n) dA[n] = __expf(dlt * Ac[n]);
    }
  };

  if (half == 0) {
    const int tb = (r0 < 0) ? 0 : r0;
    const int outg0 = (c0 - tb) >> 3;        // first output group (4 or 0)
    const int ng = (c0 + CHUNK - tb) >> 3;   // 12 or 8
    for (int g = 0; g < ng; ++g) {
      const int t0 = tb + g * 8;
      const bool out = (g >= outg0);
      float xg[8], dg[8], wg[8];
      #pragma unroll
      for (int j = 0; j < 8; ++j) {
        const size_t r = rowbase + t0 + j;
        const float2 xd = *(const float2*)&xd_g[r * (2 * C_CH) + c * 2];
        xg[j] = xd.x;
        dg[j] = xd.y;
        wg[j] = out ? wbuf[r * C_CH + c] : 0.0f;
      }
      #pragma unroll
      for (int j = 0; j < 8; ++j) {
        const int t = t0 + j;
        const int p = t - r0;
        const float dlt = dg[j];
        const float xiv = xg[j];
        const float u = dlt * xiv;
        const float4 b0 = *(const float4*)&bc[p * 16];
        const float4 b1 = *(const float4*)&bc[p * 16 + 4];
        float dA[8];
        decay8(dlt, dA);
        h[0] = dA[0] * h[0] + u * b0.x;
        h[1] = dA[1] * h[1] + u * b0.y;
        h[2] = dA[2] * h[2] + u * b0.z;
        h[3] = dA[3] * h[3] + u * b0.w;
        h[4] = dA[4] * h[4] + u * b1.x;
        h[5] = dA[5] * h[5] + u * b1.y;
        h[6] = dA[6] * h[6] + u * b1.z;
        h[7] = dA[7] * h[7] + u * b1.w;
        if (out) {
          const float4 cc0 = *(const float4*)&bc[p * 16 + 8];
          const float4 cc1 = *(const float4*)&bc[p * 16 + 12];
          float y = xiv * Dd;
          y += h[0] * cc0.x + h[1] * cc0.y + h[2] * cc0.z + h[3] * cc0.w;
          y += h[4] * cc1.x + h[5] * cc1.y + h[6] * cc1.z + h[7] * cc1.w;
          float contrib = y * wg[j];
          contrib += __shfl_xor(contrib, 1);
          contrib += __shfl_xor(contrib, 2);
          contrib += __shfl_xor(contrib, 4);
          contrib += __shfl_xor(contrib, 8);
          contrib += __shfl_xor(contrib, 16);
          contrib += __shfl_xor(contrib, 32);
          if ((tid & 63) == 0) atomicAdd(&logit[rowbase + t], contrib);
        }
      }
    }
  } else {
    const int te2e = r0 + REGION;
    const int te2 = (te2e > T_TOK) ? T_TOK : te2e;
    const int outg0 = (te2 - (c0 + CHUNK)) >> 3;  // 4 or 0
    const int ng = (te2 - c0) >> 3;               // 12 or 8
    for (int g = 0; g < ng; ++g) {
      const int t0 = te2 - 1 - g * 8;
      const bool out = (g >= outg0);
      float xg[8], dg[8], wg[8];
      #pragma unroll
      for (int j = 0; j < 8; ++j) {
        const size_t r = rowbase + t0 - j;
        const float2 xd = *(const float2*)&xd_g[r * (2 * C_CH) + c * 2];
        xg[j] = xd.x;
        dg[j] = xd.y;
        wg[j] = out ? wbuf[r * C_CH + c] : 0.0f;
      }
      #pragma unroll
      for (int j = 0; j < 8; ++j) {
        const int t = t0 - j;
        const int p = t - r0;
        const float dlt = dg[j];
        const float xiv = xg[j];
        const float u = dlt * xiv;
        const float4 b0 = *(const float4*)&bc[p * 16];
        const float4 b1 = *(const float4*)&bc[p * 16 + 4];
        float dA[8];
        decay8(dlt, dA);
        h[0] = dA[0] * h[0] + u * b0.x;
        h[1] = dA[1] * h[1] + u * b0.y;
        h[2] = dA[2] * h[2] + u * b0.z;
        h[3] = dA[3] * h[3] + u * b0.w;
        h[4] = dA[4] * h[4] + u * b1.x;
        h[5] = dA[5] * h[5] + u * b1.y;
        h[6] = dA[6] * h[6] + u * b1.z;
        h[7] = dA[7] * h[7] + u * b1.w;
        if (out) {
          const float4 cc0 = *(const float4*)&bc[p * 16 + 8];
          const float4 cc1 = *(const float4*)&bc[p * 16 + 12];
          float y = xiv * Dd;
          y += h[0] * cc0.x + h[1] * cc0.y + h[2] * cc0.z + h[3] * cc0.w;
          y += h[4] * cc1.x + h[5] * cc1.y + h[6] * cc1.z + h[7] * cc1.w;
          float contrib = y * wg[j];
          contrib += __shfl_xor(contrib, 1);
          contrib += __shfl_xor(contrib, 2);
          contrib += __shfl_xor(contrib, 4);
          contrib += __shfl_xor(contrib, 8);
          contrib += __shfl_xor(contrib, 16);
          contrib += __shfl_xor(contrib, 32);
          if ((tid & 63) == 0) atomicAdd(&logit[rowbase + t], contrib);
        }
      }
    }
  }
}

// ---------------------------------------------------------------------------
// K4: threshold (sigmoid(lg)>0.5 <=> lg>0, exact) + 3x3 max pool. ego -> 1.
// ---------------------------------------------------------------------------
__global__ __launch_bounds__(128) void k4_pool(
    const float* __restrict__ logit, const int* __restrict__ slot,
    float* __restrict__ out)
{
  const int w = threadIdx.x;
  if (w >= W_IMG) return;
  const int hh = blockIdx.x;
  const int f = blockIdx.y;
  const int s = slot[f];
  float m = 0.0f;
  if (s < 0) {
    m = 1.0f;
  } else {
    for (int dh = -1; dh <= 1; ++dh) {
      const int h2 = hh + dh;
      if (h2 < 0 || h2 >= H_IMG) continue;
      for (int dw = -1; dw <= 1; ++dw) {
        const int w2 = w + dw;
        if (w2 < 0 || w2 >= W_IMG) continue;
        if (logit[(size_t)s * T_TOK + h2 * W_IMG + w2] > 0.0f) m = 1.0f;
      }
    }
  }
  out[(size_t)f * T_TOK + hh * W_IMG + w] = m;
}

// ---------------------------------------------------------------------------
extern "C" void kernel_launch(void* const* d_in, const int* in_sizes, int n_in,
                              void* d_out, int out_size, void* d_ws, size_t ws_size,
                              hipStream_t stream) {
  const float* feats      = (const float*)d_in[0];
  const float* in_proj    = (const float*)d_in[1];
  const float* conv_w     = (const float*)d_in[2];
  const float* conv_b     = (const float*)d_in[3];
  const float* x_proj_w   = (const float*)d_in[4];
  const float* dt_proj_w  = (const float*)d_in[5];
  const float* dt_proj_b  = (const float*)d_in[6];
  const float* A_log_f    = (const float*)d_in[7];
  const float* A_log_b    = (const float*)d_in[8];
  const float* D_f        = (const float*)d_in[9];
  const float* D_b        = (const float*)d_in[10];
  const float* out_proj_w = (const float*)d_in[11];
  const float* rms_w      = (const float*)d_in[12];
  const float* mlp_w      = (const float*)d_in[13];
  const float* mlp_b      = (const float*)d_in[14];
  const int*   rec        = (const int*)d_in[15];   // int32! (jax downcasts int64)

  const int N = in_sizes[0] / (C_CH * T_TOK);
  const int n_groups = in_sizes[15];
  int S = N - n_groups;
  if (S < 1) S = 1;

  // workspace carve-up (~104 MB + 192 KB B-planes at S=7)
  char* p = (char*)d_ws;
  float* vvec  = (float*)p; p += 1024;
  int*   slot  = (int*)p;   p += ((N * 4 + 255) / 256) * 256;
  unsigned short* Bpk = (unsigned short*)p; p += 3 * BPLANE * 2;
  float* logit = (float*)p; p += (size_t)S * T_TOK * 4;
  float* wA    = (float*)p; p += (size_t)S * T_TOK * C_CH * 4;
  float* xd    = (float*)p; p += (size_t)S * T_TOK * (2 * C_CH) * 4;  // {xi,delta}
  float* bcg   = (float*)p; p += (size_t)S * T_TOK * 16 * 4;
  (void)ws_size; (void)n_in; (void)out_size;

  k0_setup<<<33, 256, 0, stream>>>(rec, n_groups, N, out_proj_w, mlp_w, in_proj,
                                   vvec, slot, Bpk);
  k12_gemmproj<<<dim3(T_TOK / 64, N), 256, 0, stream>>>(
      feats, in_proj, rms_w, mlp_w, mlp_b, vvec,
      conv_w, conv_b, x_proj_w, dt_proj_w, dt_proj_b, slot, Bpk,
      wA, logit, xd, bcg);
  k3_scan<<<dim3(T_TOK / CHUNK, N), 256, 0, stream>>>(
      xd, wA, bcg, A_log_f, A_log_b, D_f, D_b, slot, logit);
  k4_pool<<<dim3(H_IMG, N), 128, 0, stream>>>(logit, slot, (float*)d_out);
}